// Round 3
// baseline (1529.365 us; speedup 1.0000x reference)
//
#include <hip/hip_runtime.h>
#include <hip/hip_bf16.h>

typedef __hip_bfloat16 bf16;

#define PTOT  65536   // b * h * w = 16 * 4096
#define NPOS  4096    // h * w
#define CIN   256
#define HID   512
#define HD    64

__device__ __forceinline__ float us2f(unsigned short u) {
    return __uint_as_float(((unsigned int)u) << 16);
}
template<bool BF> __device__ __forceinline__ float ld1(const void* p, size_t i) {
    if (BF) return us2f(((const unsigned short*)p)[i]);
    return ((const float*)p)[i];
}
template<bool BF> __device__ __forceinline__ float4 ld4(const void* p, size_t i) {
    if (BF) {
        ushort4 u = *(const ushort4*)((const unsigned short*)p + i);
        return make_float4(us2f(u.x), us2f(u.y), us2f(u.z), us2f(u.w));
    }
    return *(const float4*)((const float*)p + i);
}
__device__ __forceinline__ float ldf(const void* p, size_t i, bool bf) {
    return bf ? us2f(((const unsigned short*)p)[i]) : ((const float*)p)[i];
}

// ---------------------------------------------------------------- dtype detector
// bf16-pair words carry a bf16 exponent in bits 14..8 (clusters in [58,66] for
// N(0,1) data); fp32 words have ~uniform mantissa bits there (~7% hit).
__global__ __launch_bounds__(256) void k_detect(const unsigned* __restrict__ x,
                                                int* __restrict__ flag) {
    int t = threadIdx.x;
    unsigned w = x[(size_t)t * 997];
    unsigned e7 = (w >> 8) & 0x7f;
    __shared__ int s[256];
    s[t] = (e7 >= 58 && e7 <= 66) ? 1 : 0;
    __syncthreads();
    for (int k = 128; k > 0; k >>= 1) { if (t < k) s[t] += s[t + k]; __syncthreads(); }
    if (t == 0) flag[0] = (s[0] >= 128) ? 1 : 0;
}

__global__ void k_relay(const int* __restrict__ src, int* __restrict__ dst) {
    dst[0] = src[0];
}

// ---------------------------------------------------------------- K0: per-position rmsnorm scale
template<bool BF>
__device__ __forceinline__ void norm_scale_body(const void* x, float* scale) {
    int p = blockIdx.x * 256 + threadIdx.x;
    int b = p >> 12, pos = p & 4095;
    float ss = 0.f;
    for (int c = 0; c < CIN; ++c) {
        float v = ld1<BF>(x, ((size_t)(b * CIN + c) << 12) + pos);
        ss += v * v;
    }
    scale[p] = 16.0f / fmaxf(sqrtf(ss), 1e-12f);
}
__global__ __launch_bounds__(256) void k_norm_scale(const void* __restrict__ x,
        float* __restrict__ scale, const int* __restrict__ flag) {
    if (flag[0]) norm_scale_body<true>(x, scale);
    else         norm_scale_body<false>(x, scale);
}

// ---------------------------------------------------------------- GEMM: C[o][P] = W[wrow0+o][k] * A[k][P] (+bias)
// FUSEA: A is input x [b][c][pos] with rmsnorm fused (scale[p] * g[c]); else A is bf16 intermediate [k][P].
template<int KTOT, bool BIAS, bool OUTF32, bool FUSEA, bool BF>
__device__ __forceinline__ void gemm_body(float* Ws, float* As,
        const void* __restrict__ W, int wrow0, const void* __restrict__ A,
        const float* __restrict__ scale, const void* __restrict__ gvec,
        const void* __restrict__ bias, void* __restrict__ Cout)
{
    const int tid = threadIdx.x;
    const int tx = tid & 15, ty = tid >> 4;
    const int o0 = blockIdx.y * 64, p0 = blockIdx.x * 64;
    float acc[4][4] = {};
    for (int k0 = 0; k0 < KTOT; k0 += 16) {
        {   // W tile: 64 o x 16 k
            int oi = tid >> 2, k4 = (tid & 3) << 2;
            float4 u = ld4<BF>(W, (size_t)(wrow0 + o0 + oi) * KTOT + k0 + k4);
            Ws[(k4 + 0) * 65 + oi] = u.x;
            Ws[(k4 + 1) * 65 + oi] = u.y;
            Ws[(k4 + 2) * 65 + oi] = u.z;
            Ws[(k4 + 3) * 65 + oi] = u.w;
        }
        {   // A tile: 16 k x 64 p
            int ki = tid >> 4, p4 = (tid & 15) << 2;
            int p = p0 + p4;
            float4 f;
            if (FUSEA) {
                int c = k0 + ki;
                int bb = p >> 12, pos = p & 4095;
                float4 u = ld4<BF>(A, ((size_t)(bb * CIN + c) << 12) + pos);
                float4 sc = *(const float4*)&scale[p];
                float gv = ld1<BF>(gvec, c);
                f = make_float4(u.x * sc.x * gv, u.y * sc.y * gv,
                                u.z * sc.z * gv, u.w * sc.w * gv);
            } else {
                f = ld4<true>(A, (size_t)(k0 + ki) * PTOT + p);   // intermediates are bf16
            }
            *(float4*)&As[ki * 68 + p4] = f;
        }
        __syncthreads();
        #pragma unroll
        for (int kk = 0; kk < 16; ++kk) {
            float a[4], bb[4];
            #pragma unroll
            for (int i = 0; i < 4; ++i) a[i] = Ws[kk * 65 + ty * 4 + i];
            #pragma unroll
            for (int j = 0; j < 4; ++j) bb[j] = As[kk * 68 + j * 16 + tx];
            #pragma unroll
            for (int i = 0; i < 4; ++i)
                #pragma unroll
                for (int j = 0; j < 4; ++j)
                    acc[i][j] = fmaf(a[i], bb[j], acc[i][j]);
        }
        __syncthreads();
    }
    #pragma unroll
    for (int i = 0; i < 4; ++i) {
        int o = o0 + ty * 4 + i;
        float bv = BIAS ? ld1<BF>(bias, o) : 0.0f;
        #pragma unroll
        for (int j = 0; j < 4; ++j) {
            int p = p0 + j * 16 + tx;
            float v = acc[i][j] + bv;
            if (OUTF32) ((float*)Cout)[(size_t)o * PTOT + p] = v;
            else        ((bf16*)Cout)[(size_t)o * PTOT + p] = __float2bfloat16(v);
        }
    }
}
template<int KTOT, bool BIAS, bool OUTF32, bool FUSEA>
__global__ __launch_bounds__(256) void k_gemm(
        const void* __restrict__ W, int wrow0, const void* __restrict__ A,
        const float* __restrict__ scale, const void* __restrict__ gvec,
        const void* __restrict__ bias, void* __restrict__ Cout,
        const int* __restrict__ flag)
{
    __shared__ float Ws[16 * 65];
    __shared__ float As[16 * 68];
    if (flag[0]) gemm_body<KTOT, BIAS, OUTF32, FUSEA, true >(Ws, As, W, wrow0, A, scale, gvec, bias, Cout);
    else         gemm_body<KTOT, BIAS, OUTF32, FUSEA, false>(Ws, As, W, wrow0, A, scale, gvec, bias, Cout);
}

// ---------------------------------------------------------------- K3: k row stats (max, 1/sumexp) over n=4100
__global__ __launch_bounds__(256) void k_kstats(
        const bf16* __restrict__ kv, const void* __restrict__ memkv,
        float* __restrict__ rowmax, float* __restrict__ rowinv,
        const int* __restrict__ flag)
{
    bool bf = flag[0] != 0;
    int r = blockIdx.x;                 // b*512 + h*64 + d
    int b = r >> 9, hd = r & 511;
    const bf16* krow = kv + (size_t)hd * PTOT + b * NPOS;
    int t = threadIdx.x;
    float vals[16];
    float m = -1e30f;
    #pragma unroll
    for (int i = 0; i < 16; ++i) {
        vals[i] = us2f(((const unsigned short*)krow)[t + (i << 8)]);
        m = fmaxf(m, vals[i]);
    }
    float mv = (t < 4) ? ldf(memkv, hd * 4 + t, bf) : -1e30f;
    m = fmaxf(m, mv);
    __shared__ float red[256];
    red[t] = m; __syncthreads();
    for (int s = 128; s > 0; s >>= 1) {
        if (t < s) red[t] = fmaxf(red[t], red[t + s]);
        __syncthreads();
    }
    float M = red[0]; __syncthreads();
    float sum = 0.f;
    #pragma unroll
    for (int i = 0; i < 16; ++i) sum += expf(vals[i] - M);
    if (t < 4) sum += expf(mv - M);
    red[t] = sum; __syncthreads();
    for (int s = 128; s > 0; s >>= 1) {
        if (t < s) red[t] += red[t + s];
        __syncthreads();
    }
    if (t == 0) { rowmax[r] = M; rowinv[r] = 1.0f / red[0]; }
}

// ---------------------------------------------------------------- K4: context partials ct[d][e] = sum_n ksm[d][n]*v[e][n]
__global__ __launch_bounds__(256) void k_context(
        const bf16* __restrict__ kv, const void* __restrict__ memkv,
        const float* __restrict__ rowmax, const float* __restrict__ rowinv,
        float* __restrict__ ctpart, const int* __restrict__ flag)
{
    bool bf = flag[0] != 0;
    int bh = blockIdx.x, chunk = blockIdx.y;
    int b = bh >> 3, h = bh & 7;
    __shared__ float kS[64 * 66];       // [d][nn]
    __shared__ float vS[64 * 68];       // [nn][e]
    __shared__ float rmS[64], riS[64];
    int tid = threadIdx.x;
    if (tid < 64) {
        rmS[tid] = rowmax[(b << 9) + (h << 6) + tid];
        riS[tid] = rowinv[(b << 9) + (h << 6) + tid];
    }
    int d = tid >> 2, e0 = (tid & 3) << 4;
    float acc[16] = {};
    const unsigned short* kbase = (const unsigned short*)kv + (size_t)(h * HD) * PTOT + b * NPOS + chunk * 1024;
    const unsigned short* vbase = (const unsigned short*)kv + (size_t)(HID + h * HD) * PTOT + b * NPOS + chunk * 1024;
    for (int t0 = 0; t0 < 1024; t0 += 64) {
        __syncthreads();
        #pragma unroll
        for (int l = 0; l < 16; ++l) {
            int idx = tid + (l << 8);
            int ci = idx >> 6, ni = idx & 63;
            float kvv = us2f(kbase[(size_t)ci * PTOT + t0 + ni]);
            kS[ci * 66 + ni] = expf(kvv - rmS[ci]) * riS[ci];
            vS[ni * 68 + ci] = us2f(vbase[(size_t)ci * PTOT + t0 + ni]);
        }
        __syncthreads();
        #pragma unroll 8
        for (int nn = 0; nn < 64; ++nn) {
            float kd = kS[d * 66 + nn];
            const float4* vr = (const float4*)&vS[nn * 68 + e0];
            float4 v0 = vr[0], v1 = vr[1], v2 = vr[2], v3 = vr[3];
            acc[0]  = fmaf(kd, v0.x, acc[0]);  acc[1]  = fmaf(kd, v0.y, acc[1]);
            acc[2]  = fmaf(kd, v0.z, acc[2]);  acc[3]  = fmaf(kd, v0.w, acc[3]);
            acc[4]  = fmaf(kd, v1.x, acc[4]);  acc[5]  = fmaf(kd, v1.y, acc[5]);
            acc[6]  = fmaf(kd, v1.z, acc[6]);  acc[7]  = fmaf(kd, v1.w, acc[7]);
            acc[8]  = fmaf(kd, v2.x, acc[8]);  acc[9]  = fmaf(kd, v2.y, acc[9]);
            acc[10] = fmaf(kd, v2.z, acc[10]); acc[11] = fmaf(kd, v2.w, acc[11]);
            acc[12] = fmaf(kd, v3.x, acc[12]); acc[13] = fmaf(kd, v3.y, acc[13]);
            acc[14] = fmaf(kd, v3.z, acc[14]); acc[15] = fmaf(kd, v3.w, acc[15]);
        }
    }
    if (chunk == 0) {   // memory K/V contribution (n = 0..3 of the concat)
        float rm = rmS[d], ri = riS[d];
        #pragma unroll
        for (int mm = 0; mm < 4; ++mm) {
            float kw = expf(ldf(memkv, ((h << 6) + d) * 4 + mm, bf) - rm) * ri;
            #pragma unroll
            for (int j = 0; j < 16; ++j)
                acc[j] = fmaf(kw, ldf(memkv, 2048 + ((h << 6) + e0 + j) * 4 + mm, bf), acc[j]);
        }
    }
    float* outp = ctpart + (size_t)(chunk * 128 + bh) * 4096 + d * 64 + e0;
    #pragma unroll
    for (int q = 0; q < 4; ++q)
        *(float4*)(outp + 4 * q) = make_float4(acc[4*q], acc[4*q+1], acc[4*q+2], acc[4*q+3]);
}

// ---------------------------------------------------------------- K5: q softmax (over d) + out[e][n] = sum_d ct[d][e]*q[d][n]
__global__ __launch_bounds__(256) void k_apply(
        const bf16* __restrict__ qbuf, const float* __restrict__ ctpart,
        bf16* __restrict__ oat)
{
    int blk = blockIdx.x;
    int pt = blk & 15, h = (blk >> 4) & 7, b = blk >> 7;
    __shared__ float ctS[4096];   // [d][e]
    int tid = threadIdx.x;
    int bh = b * 8 + h;
    for (int l = 0; l < 16; ++l) {
        int idx = tid + (l << 8);
        float s = 0.f;
        #pragma unroll
        for (int c = 0; c < 4; ++c) s += ctpart[(size_t)(c * 128 + bh) * 4096 + idx];
        ctS[idx] = s;
    }
    __syncthreads();
    int n = pt * 256 + tid;
    const unsigned short* qbase = (const unsigned short*)qbuf + (size_t)(h * HD) * PTOT + b * NPOS + n;
    float qs[64];
    float m = -1e30f;
    #pragma unroll
    for (int d2 = 0; d2 < 64; ++d2) { qs[d2] = us2f(qbase[(size_t)d2 * PTOT]); m = fmaxf(m, qs[d2]); }
    float s = 0.f;
    #pragma unroll
    for (int d2 = 0; d2 < 64; ++d2) { qs[d2] = expf(qs[d2] - m); s += qs[d2]; }
    float inv = 0.125f / s;       // fold scale = HEAD_DIM^-0.5 = 1/8 into softmax normalizer
    #pragma unroll
    for (int d2 = 0; d2 < 64; ++d2) qs[d2] *= inv;
    bf16* obase = oat + (size_t)(h * HD) * PTOT + b * NPOS + n;
    #pragma unroll
    for (int ec = 0; ec < 4; ++ec) {
        float acc[16] = {};
        #pragma unroll
        for (int d2 = 0; d2 < 64; ++d2) {
            float qd = qs[d2];
            const float4* cr = (const float4*)&ctS[d2 * 64 + ec * 16];
            float4 c0 = cr[0], c1 = cr[1], c2 = cr[2], c3 = cr[3];
            acc[0]  = fmaf(qd, c0.x, acc[0]);  acc[1]  = fmaf(qd, c0.y, acc[1]);
            acc[2]  = fmaf(qd, c0.z, acc[2]);  acc[3]  = fmaf(qd, c0.w, acc[3]);
            acc[4]  = fmaf(qd, c1.x, acc[4]);  acc[5]  = fmaf(qd, c1.y, acc[5]);
            acc[6]  = fmaf(qd, c1.z, acc[6]);  acc[7]  = fmaf(qd, c1.w, acc[7]);
            acc[8]  = fmaf(qd, c2.x, acc[8]);  acc[9]  = fmaf(qd, c2.y, acc[9]);
            acc[10] = fmaf(qd, c2.z, acc[10]); acc[11] = fmaf(qd, c2.w, acc[11]);
            acc[12] = fmaf(qd, c3.x, acc[12]); acc[13] = fmaf(qd, c3.y, acc[13]);
            acc[14] = fmaf(qd, c3.z, acc[14]); acc[15] = fmaf(qd, c3.w, acc[15]);
        }
        #pragma unroll
        for (int j = 0; j < 16; ++j)
            obase[(size_t)(ec * 16 + j) * PTOT] = __float2bfloat16(acc[j]);
    }
}

// ---------------------------------------------------------------- K7: rmsnorm(pre) -> d_out [b][c][pos], dtype per flag
template<bool BF>
__device__ __forceinline__ void rmsout_body(const float* pre, const void* g, void* out) {
    int p = blockIdx.x * 256 + threadIdx.x;
    int b = p >> 12, pos = p & 4095;
    float ss = 0.f;
    for (int c = 0; c < CIN; ++c) { float v = pre[(size_t)c * PTOT + p]; ss += v * v; }
    float scale = 16.0f / fmaxf(sqrtf(ss), 1e-12f);
    for (int c = 0; c < CIN; ++c) {
        float v = pre[(size_t)c * PTOT + p] * scale * ld1<BF>(g, c);
        size_t oi = ((size_t)(b * CIN + c) << 12) + pos;
        if (BF) ((bf16*)out)[oi] = __float2bfloat16(v);
        else    ((float*)out)[oi] = v;
    }
}
__global__ __launch_bounds__(256) void k_rmsnorm_out(
        const float* __restrict__ pre, const void* __restrict__ g,
        void* __restrict__ out, const int* __restrict__ flag)
{
    if (flag[0]) rmsout_body<true>(pre, g, out);
    else         rmsout_body<false>(pre, g, out);
}

extern "C" void kernel_launch(void* const* d_in, const int* in_sizes, int n_in,
                              void* d_out, int out_size, void* d_ws, size_t ws_size,
                              hipStream_t stream) {
    const void* x     = d_in[0];
    const void* g_in  = d_in[1];
    const void* w_qkv = d_in[2];
    const void* memkv = d_in[3];
    const void* w_out = d_in[4];
    const void* b_out = d_in[5];
    const void* g_out = d_in[6];

    // ---- workspace: peak 128 MiB ----
    char* ws = (char*)d_ws;
    bf16*  kv    = (bf16*)ws;                  // [1024][65536] bf16: K rows 0..511, V rows 512..1023
    bf16*  qbuf  = (bf16*)ws;                  // [512][65536] bf16, over dead K
    bf16*  oat   = (bf16*)(ws + 67108864);     // [512][65536] bf16, over dead V
    float* pre   = (float*)ws;                 // [256][65536] f32, over dead Q
    int*   flagB = (int*)(ws + 67108864);      // relay copy, written after oat is dead

    // ---- small scratch in d_out (<= 9.1 MiB of >= 32 MiB); fully overwritten at the end ----
    char* ob = (char*)d_out;
    float* ctpart = (float*)ob;                // 8 MiB  [4][128][64][64]
    float* scale  = (float*)(ob + 8388608);    // 256 KiB [65536]
    float* rowmax = (float*)(ob + 8650752);    // 32 KiB [8192]
    float* rowinv = (float*)(ob + 8683520);    // 32 KiB [8192]
    int*   flagA  = (int*)(ob + 9437184);

    k_detect<<<1, 256, 0, stream>>>((const unsigned*)x, flagA);

    k_norm_scale<<<256, 256, 0, stream>>>(x, scale, flagA);

    // K/V = w_qkv rows 512..1535 applied to normalized x
    dim3 gkv(1024, 16);
    k_gemm<CIN, false, false, true><<<gkv, 256, 0, stream>>>(
        w_qkv, 512, x, scale, g_in, nullptr, kv, flagA);

    k_kstats<<<8192, 256, 0, stream>>>(kv, memkv, rowmax, rowinv, flagA);

    dim3 gctx(128, 4);
    k_context<<<gctx, 256, 0, stream>>>(kv, memkv, rowmax, rowinv, ctpart, flagA);

    // Q = w_qkv rows 0..511 (K region now dead)
    dim3 gq(1024, 8);
    k_gemm<CIN, false, false, true><<<gq, 256, 0, stream>>>(
        w_qkv, 0, x, scale, g_in, nullptr, qbuf, flagA);

    k_apply<<<2048, 256, 0, stream>>>(qbuf, ctpart, oat);

    dim3 go(1024, 4);
    k_gemm<HID, true, true, false><<<go, 256, 0, stream>>>(
        w_out, 0, oat, nullptr, nullptr, b_out, pre, flagA);

    k_relay<<<1, 1, 0, stream>>>(flagA, flagB);     // oat region dead now

    k_rmsnorm_out<<<256, 256, 0, stream>>>(pre, g_out, d_out, flagB);
}

// Round 4
// 595.309 us; speedup vs baseline: 2.5690x; 2.5690x over previous
//
#include <hip/hip_runtime.h>
#include <hip/hip_bf16.h>

typedef __hip_bfloat16 bf16;
typedef short bf16x8 __attribute__((ext_vector_type(8)));
typedef float f32x4 __attribute__((ext_vector_type(4)));

#define PTOT  65536   // b * h * w = 16 * 4096
#define NPOS  4096    // h * w
#define CIN   256
#define HID   512
#define HD    64

__device__ __forceinline__ float us2f(unsigned short u) {
    return __uint_as_float(((unsigned int)u) << 16);
}
__device__ __forceinline__ float ldf(const void* p, size_t i, bool bf) {
    return bf ? us2f(((const unsigned short*)p)[i]) : ((const float*)p)[i];
}
__device__ __forceinline__ unsigned short f2bs(float v) {
    __hip_bfloat16 h = __float2bfloat16(v);
    return *reinterpret_cast<unsigned short*>(&h);
}
// async global->LDS, 16 B per lane; lds dest must be wave-uniform base
__device__ __forceinline__ void gld16(const void* g, void* s) {
    __builtin_amdgcn_global_load_lds(
        (const __attribute__((address_space(1))) unsigned int*)g,
        (__attribute__((address_space(3))) unsigned int*)s, 16, 0, 0);
}

// ---------------------------------------------------------------- dtype detector
__global__ __launch_bounds__(256) void k_detect(const unsigned* __restrict__ x,
                                                int* __restrict__ flag) {
    int t = threadIdx.x;
    unsigned w = x[(size_t)t * 997];
    unsigned e7 = (w >> 8) & 0x7f;
    __shared__ int s[256];
    s[t] = (e7 >= 58 && e7 <= 66) ? 1 : 0;
    __syncthreads();
    for (int k = 128; k > 0; k >>= 1) { if (t < k) s[t] += s[t + k]; __syncthreads(); }
    if (t == 0) flag[0] = (s[0] >= 128) ? 1 : 0;
}

__global__ void k_relay(const int* __restrict__ src, int* __restrict__ dst) {
    dst[0] = src[0];
}

// ---------------------------------------------------------------- elementwise convert -> bf16
__global__ __launch_bounds__(256) void k_cvt(const void* __restrict__ src,
        unsigned short* __restrict__ dst, int n, const int* __restrict__ flag) {
    bool bf = flag[0] != 0;
    int i = blockIdx.x * 256 + threadIdx.x;
    if (i < n) dst[i] = f2bs(ldf(src, i, bf));
}

// ---------------------------------------------------------------- rmsnorm(x) -> xn bf16 [p][c] (c contiguous)
__global__ __launch_bounds__(256) void k_norm_xn(
        const void* __restrict__ x, const void* __restrict__ g,
        unsigned short* __restrict__ xn, const int* __restrict__ flag)
{
    bool bf = flag[0] != 0;
    __shared__ float xs[64][65];
    __shared__ float gS[256];
    __shared__ float sS[64];
    __shared__ float red[4][64];
    int t = threadIdx.x;
    int p0 = blockIdx.x * 64;
    int b = p0 >> 12;
    int posbase = p0 & 4095;
    gS[t] = ldf(g, t, bf);
    int pl = t & 63, cg = t >> 6;
    const size_t xbase = ((size_t)b * CIN) << 12;
    float ss = 0.f;
    for (int c = cg * 64; c < cg * 64 + 64; ++c) {
        float v = ldf(x, xbase + ((size_t)c << 12) + posbase + pl, bf);
        ss += v * v;
    }
    red[cg][pl] = ss;
    __syncthreads();
    if (t < 64) {
        float tot = red[0][t] + red[1][t] + red[2][t] + red[3][t];
        sS[t] = 16.0f / fmaxf(sqrtf(tot), 1e-12f);
    }
    for (int c0 = 0; c0 < 256; c0 += 64) {
        __syncthreads();
        #pragma unroll
        for (int r = 0; r < 16; ++r) {
            int c = c0 + r * 4 + cg;
            xs[r * 4 + cg][pl] = ldf(x, xbase + ((size_t)c << 12) + posbase + pl, bf);
        }
        __syncthreads();
        int pr = t >> 2, c4 = (t & 3) * 16;
        float sc = sS[pr];
        unsigned short tmp[16];
        #pragma unroll
        for (int j = 0; j < 16; ++j)
            tmp[j] = f2bs(xs[c4 + j][pr] * sc * gS[c0 + c4 + j]);
        unsigned short* dst = &xn[(size_t)(p0 + pr) * 256 + c0 + c4];
        *(uint4*)dst = ((uint4*)tmp)[0];
        *(uint4*)(dst + 8) = ((uint4*)tmp)[1];
    }
}

// ---------------------------------------------------------------- MFMA GEMM: C[m][p] = W[m][k] · Bm[p][k]^T
// W: [M][KTOT] bf16 rows k-contig; Bm: [PTOT][KTOT] bf16 rows k-contig; C: [M][PTOT] bf16
template<int KTOT, bool BIAS>
__global__ __launch_bounds__(256) void k_mfma(
        const bf16* __restrict__ W, const bf16* __restrict__ Bm,
        const void* __restrict__ bias, bf16* __restrict__ C,
        const int* __restrict__ flag)
{
    __shared__ __align__(16) unsigned short As[128 * 32];
    __shared__ __align__(16) unsigned short Bs[128 * 32];
    const int tid = threadIdx.x;
    const int wv = tid >> 6, lane = tid & 63;
    const int quad = lane >> 4, l16 = lane & 15;
    const int wm = wv >> 1, wn = wv & 1;
    const int m0 = blockIdx.y * 128, n0 = blockIdx.x * 128;
    f32x4 acc[4][4] = {};
    const bf16* gA = W + (size_t)(m0 + (tid >> 2)) * KTOT + (tid & 3) * 8;
    const bf16* gB = Bm + (size_t)(n0 + (tid >> 2)) * KTOT + (tid & 3) * 8;
    unsigned short* lA = As + wv * 512;   // wave-uniform; HW scatters lane*16B
    unsigned short* lB = Bs + wv * 512;
    for (int k0 = 0; k0 < KTOT; k0 += 32) {
        gld16(gA + k0, lA);
        gld16(gA + (size_t)64 * KTOT + k0, lA + 2048);
        gld16(gB + k0, lB);
        gld16(gB + (size_t)64 * KTOT + k0, lB + 2048);
        __syncthreads();
        bf16x8 bfr[4];
        #pragma unroll
        for (int j = 0; j < 4; ++j)
            bfr[j] = *(const bf16x8*)&Bs[(wn * 64 + j * 16 + l16) * 32 + quad * 8];
        #pragma unroll
        for (int i = 0; i < 4; ++i) {
            bf16x8 af = *(const bf16x8*)&As[(wm * 64 + i * 16 + l16) * 32 + quad * 8];
            #pragma unroll
            for (int j = 0; j < 4; ++j)
                acc[i][j] = __builtin_amdgcn_mfma_f32_16x16x32_bf16(af, bfr[j], acc[i][j], 0, 0, 0);
        }
        __syncthreads();
    }
    bool bf = BIAS ? (flag[0] != 0) : false;
    #pragma unroll
    for (int i = 0; i < 4; ++i) {
        int row = m0 + wm * 64 + i * 16 + quad * 4;
        #pragma unroll
        for (int r = 0; r < 4; ++r) {
            float bv = BIAS ? ldf(bias, row + r, bf) : 0.0f;
            #pragma unroll
            for (int j = 0; j < 4; ++j) {
                int col = n0 + wn * 64 + j * 16 + l16;
                C[(size_t)(row + r) * PTOT + col] = __float2bfloat16(acc[i][j][r] + bv);
            }
        }
    }
}

// ---------------------------------------------------------------- k row stats (max, 1/sumexp) over n=4100
__global__ __launch_bounds__(256) void k_kstats(
        const bf16* __restrict__ kv, const void* __restrict__ memkv,
        float* __restrict__ rowmax, float* __restrict__ rowinv,
        const int* __restrict__ flag)
{
    bool bf = flag[0] != 0;
    int r = blockIdx.x;                 // b*512 + h*64 + d
    int b = r >> 9, hd = r & 511;
    const unsigned short* krow = (const unsigned short*)kv + (size_t)hd * PTOT + b * NPOS;
    int t = threadIdx.x;
    float vals[16];
    float m = -1e30f;
    #pragma unroll
    for (int i = 0; i < 16; ++i) {
        vals[i] = us2f(krow[t + (i << 8)]);
        m = fmaxf(m, vals[i]);
    }
    float mv = (t < 4) ? ldf(memkv, hd * 4 + t, bf) : -1e30f;
    m = fmaxf(m, mv);
    __shared__ float red[256];
    red[t] = m; __syncthreads();
    for (int s = 128; s > 0; s >>= 1) {
        if (t < s) red[t] = fmaxf(red[t], red[t + s]);
        __syncthreads();
    }
    float M = red[0]; __syncthreads();
    float sum = 0.f;
    #pragma unroll
    for (int i = 0; i < 16; ++i) sum += expf(vals[i] - M);
    if (t < 4) sum += expf(mv - M);
    red[t] = sum; __syncthreads();
    for (int s = 128; s > 0; s >>= 1) {
        if (t < s) red[t] += red[t + s];
        __syncthreads();
    }
    if (t == 0) { rowmax[r] = M; rowinv[r] = 1.0f / red[0]; }
}

// ---------------------------------------------------------------- context partials ct[d][e] = sum_n ksm[d][n]*v[e][n]
__global__ __launch_bounds__(256) void k_context(
        const bf16* __restrict__ kv, const void* __restrict__ memkv,
        const float* __restrict__ rowmax, const float* __restrict__ rowinv,
        float* __restrict__ ctpart, const int* __restrict__ flag)
{
    bool bf = flag[0] != 0;
    int bh = blockIdx.x, chunk = blockIdx.y;
    int b = bh >> 3, h = bh & 7;
    __shared__ float kS[64 * 66];       // [d][nn]
    __shared__ float vS[64 * 68];       // [nn][e]
    __shared__ float rmS[64], riS[64];
    int tid = threadIdx.x;
    if (tid < 64) {
        rmS[tid] = rowmax[(b << 9) + (h << 6) + tid];
        riS[tid] = rowinv[(b << 9) + (h << 6) + tid];
    }
    int d = tid >> 2, e0 = (tid & 3) << 4;
    float acc[16] = {};
    const unsigned short* kbase = (const unsigned short*)kv + (size_t)(h * HD) * PTOT + b * NPOS + chunk * 1024;
    const unsigned short* vbase = (const unsigned short*)kv + (size_t)(HID + h * HD) * PTOT + b * NPOS + chunk * 1024;
    for (int t0 = 0; t0 < 1024; t0 += 64) {
        __syncthreads();
        #pragma unroll
        for (int l = 0; l < 16; ++l) {
            int idx = tid + (l << 8);
            int ci = idx >> 6, ni = idx & 63;
            float kvv = us2f(kbase[(size_t)ci * PTOT + t0 + ni]);
            kS[ci * 66 + ni] = expf(kvv - rmS[ci]) * riS[ci];
            vS[ni * 68 + ci] = us2f(vbase[(size_t)ci * PTOT + t0 + ni]);
        }
        __syncthreads();
        #pragma unroll 8
        for (int nn = 0; nn < 64; ++nn) {
            float kd = kS[d * 66 + nn];
            const float4* vr = (const float4*)&vS[nn * 68 + e0];
            float4 v0 = vr[0], v1 = vr[1], v2 = vr[2], v3 = vr[3];
            acc[0]  = fmaf(kd, v0.x, acc[0]);  acc[1]  = fmaf(kd, v0.y, acc[1]);
            acc[2]  = fmaf(kd, v0.z, acc[2]);  acc[3]  = fmaf(kd, v0.w, acc[3]);
            acc[4]  = fmaf(kd, v1.x, acc[4]);  acc[5]  = fmaf(kd, v1.y, acc[5]);
            acc[6]  = fmaf(kd, v1.z, acc[6]);  acc[7]  = fmaf(kd, v1.w, acc[7]);
            acc[8]  = fmaf(kd, v2.x, acc[8]);  acc[9]  = fmaf(kd, v2.y, acc[9]);
            acc[10] = fmaf(kd, v2.z, acc[10]); acc[11] = fmaf(kd, v2.w, acc[11]);
            acc[12] = fmaf(kd, v3.x, acc[12]); acc[13] = fmaf(kd, v3.y, acc[13]);
            acc[14] = fmaf(kd, v3.z, acc[14]); acc[15] = fmaf(kd, v3.w, acc[15]);
        }
    }
    if (chunk == 0) {   // memory K/V contribution (n = 0..3 of the concat)
        float rm = rmS[d], ri = riS[d];
        #pragma unroll
        for (int mm = 0; mm < 4; ++mm) {
            float kw = expf(ldf(memkv, ((h << 6) + d) * 4 + mm, bf) - rm) * ri;
            #pragma unroll
            for (int j = 0; j < 16; ++j)
                acc[j] = fmaf(kw, ldf(memkv, 2048 + ((h << 6) + e0 + j) * 4 + mm, bf), acc[j]);
        }
    }
    float* outp = ctpart + (size_t)(chunk * 128 + bh) * 4096 + d * 64 + e0;
    #pragma unroll
    for (int q = 0; q < 4; ++q)
        *(float4*)(outp + 4 * q) = make_float4(acc[4*q], acc[4*q+1], acc[4*q+2], acc[4*q+3]);
}

// ---------------------------------------------------------------- q softmax + out; writes oat_pe [p][e] (e contiguous)
__global__ __launch_bounds__(256) void k_apply(
        const bf16* __restrict__ qbuf, const float* __restrict__ ctpart,
        unsigned short* __restrict__ oat_pe)
{
    int blk = blockIdx.x;
    int pt = blk & 15, h = (blk >> 4) & 7, b = blk >> 7;
    __shared__ float ctS[4096];   // [d][e]
    int tid = threadIdx.x;
    int bh = b * 8 + h;
    for (int l = 0; l < 16; ++l) {
        int idx = tid + (l << 8);
        float s = 0.f;
        #pragma unroll
        for (int c = 0; c < 4; ++c) s += ctpart[(size_t)(c * 128 + bh) * 4096 + idx];
        ctS[idx] = s;
    }
    __syncthreads();
    int n = pt * 256 + tid;
    const unsigned short* qbase = (const unsigned short*)qbuf + (size_t)(h * HD) * PTOT + b * NPOS + n;
    float qs[64];
    float m = -1e30f;
    #pragma unroll
    for (int d2 = 0; d2 < 64; ++d2) { qs[d2] = us2f(qbase[(size_t)d2 * PTOT]); m = fmaxf(m, qs[d2]); }
    float s = 0.f;
    #pragma unroll
    for (int d2 = 0; d2 < 64; ++d2) { qs[d2] = expf(qs[d2] - m); s += qs[d2]; }
    float inv = 0.125f / s;
    #pragma unroll
    for (int d2 = 0; d2 < 64; ++d2) qs[d2] *= inv;
    unsigned short* obase = oat_pe + (size_t)(b * NPOS + n) * HID + h * HD;
    #pragma unroll
    for (int ec = 0; ec < 4; ++ec) {
        float acc[16] = {};
        #pragma unroll
        for (int d2 = 0; d2 < 64; ++d2) {
            float qd = qs[d2];
            const float4* cr = (const float4*)&ctS[d2 * 64 + ec * 16];
            float4 c0 = cr[0], c1 = cr[1], c2 = cr[2], c3 = cr[3];
            acc[0]  = fmaf(qd, c0.x, acc[0]);  acc[1]  = fmaf(qd, c0.y, acc[1]);
            acc[2]  = fmaf(qd, c0.z, acc[2]);  acc[3]  = fmaf(qd, c0.w, acc[3]);
            acc[4]  = fmaf(qd, c1.x, acc[4]);  acc[5]  = fmaf(qd, c1.y, acc[5]);
            acc[6]  = fmaf(qd, c1.z, acc[6]);  acc[7]  = fmaf(qd, c1.w, acc[7]);
            acc[8]  = fmaf(qd, c2.x, acc[8]);  acc[9]  = fmaf(qd, c2.y, acc[9]);
            acc[10] = fmaf(qd, c2.z, acc[10]); acc[11] = fmaf(qd, c2.w, acc[11]);
            acc[12] = fmaf(qd, c3.x, acc[12]); acc[13] = fmaf(qd, c3.y, acc[13]);
            acc[14] = fmaf(qd, c3.z, acc[14]); acc[15] = fmaf(qd, c3.w, acc[15]);
        }
        unsigned short tmp[16];
        #pragma unroll
        for (int j = 0; j < 16; ++j) tmp[j] = f2bs(acc[j]);
        *(uint4*)(obase + ec * 16) = ((uint4*)tmp)[0];
        *(uint4*)(obase + ec * 16 + 8) = ((uint4*)tmp)[1];
    }
}

// ---------------------------------------------------------------- rmsnorm(pre bf16) -> d_out [b][c][pos]
template<bool BF>
__device__ __forceinline__ void rmsout_body(const unsigned short* pre, const void* g, void* out) {
    int p = blockIdx.x * 256 + threadIdx.x;
    int b = p >> 12, pos = p & 4095;
    float ss = 0.f;
    for (int c = 0; c < CIN; ++c) { float v = us2f(pre[(size_t)c * PTOT + p]); ss += v * v; }
    float scale = 16.0f / fmaxf(sqrtf(ss), 1e-12f);
    for (int c = 0; c < CIN; ++c) {
        float v = us2f(pre[(size_t)c * PTOT + p]) * scale * (BF ? us2f(((const unsigned short*)g)[c]) : ((const float*)g)[c]);
        size_t oi = ((size_t)(b * CIN + c) << 12) + pos;
        if (BF) ((unsigned short*)out)[oi] = f2bs(v);
        else    ((float*)out)[oi] = v;
    }
}
__global__ __launch_bounds__(256) void k_rmsnorm_out(
        const unsigned short* __restrict__ pre, const void* __restrict__ g,
        void* __restrict__ out, const int* __restrict__ flag)
{
    if (flag[0]) rmsout_body<true>(pre, g, out);
    else         rmsout_body<false>(pre, g, out);
}

extern "C" void kernel_launch(void* const* d_in, const int* in_sizes, int n_in,
                              void* d_out, int out_size, void* d_ws, size_t ws_size,
                              hipStream_t stream) {
    const void* x     = d_in[0];
    const void* g_in  = d_in[1];
    const void* w_qkv = d_in[2];
    const void* memkv = d_in[3];
    const void* w_out = d_in[4];
    const void* b_out = d_in[5];
    const void* g_out = d_in[6];

    // ---- workspace: peak 128 MiB (same as passing R3) ----
    char* ws = (char*)d_ws;
    bf16*           kv     = (bf16*)ws;                    // [1024][65536] bf16: K rows 0..511, V 512..1023
    bf16*           qbuf   = (bf16*)ws;                    // [512][65536] bf16, over dead K
    unsigned short* oat_pe = (unsigned short*)(ws + 67108864); // [65536][512] bf16, over dead V
    unsigned short* pre    = (unsigned short*)ws;          // [256][65536] bf16, over dead qbuf
    int*            flagB  = (int*)(ws + 50331648);        // dead zone (upper qbuf) at relay time

    // ---- scratch in d_out (~45 MB of 67 MB); all dead before final overwrite ----
    char* ob = (char*)d_out;
    float*          ctpart = (float*)ob;                   // 8 MiB  [4][128][64][64]
    float*          rowmax = (float*)(ob + 8388608);       // 32 KiB
    float*          rowinv = (float*)(ob + 8421376);       // 32 KiB
    int*            flagA  = (int*)(ob + 8454144);         // 4 B
    unsigned short* wq_b   = (unsigned short*)(ob + 9437184);   // 1536*256 bf16 = 768 KiB
    unsigned short* wout_b = (unsigned short*)(ob + 10485760);  // 256*512 bf16 = 256 KiB
    unsigned short* xn     = (unsigned short*)(ob + 12582912);  // [65536][256] bf16 = 32 MiB

    k_detect<<<1, 256, 0, stream>>>((const unsigned*)x, flagA);

    k_cvt<<<1536, 256, 0, stream>>>(w_qkv, wq_b, 1536 * 256, flagA);
    k_cvt<<<512, 256, 0, stream>>>(w_out, wout_b, 256 * 512, flagA);

    k_norm_xn<<<1024, 256, 0, stream>>>(x, g_in, xn, flagA);

    // K/V = w_qkv rows 512..1535: C[1024][PTOT]
    dim3 gkv(512, 8);
    k_mfma<CIN, false><<<gkv, 256, 0, stream>>>(
        (const bf16*)(wq_b + (size_t)512 * CIN), (const bf16*)xn, nullptr, kv, flagA);

    k_kstats<<<8192, 256, 0, stream>>>(kv, memkv, rowmax, rowinv, flagA);

    dim3 gctx(128, 4);
    k_context<<<gctx, 256, 0, stream>>>(kv, memkv, rowmax, rowinv, ctpart, flagA);

    // Q = w_qkv rows 0..511 (K region dead after context)
    dim3 gq(512, 4);
    k_mfma<CIN, false><<<gq, 256, 0, stream>>>(
        (const bf16*)wq_b, (const bf16*)xn, nullptr, qbuf, flagA);

    k_apply<<<2048, 256, 0, stream>>>(qbuf, ctpart, oat_pe);

    // pre[256][PTOT] = w_out[256][512] · oat_pe[p][512]^T + b_out
    dim3 go(512, 2);
    k_mfma<HID, true><<<go, 256, 0, stream>>>(
        (const bf16*)wout_b, (const bf16*)oat_pe, b_out, (bf16*)pre, flagA);

    k_relay<<<1, 1, 0, stream>>>(flagA, flagB);

    k_rmsnorm_out<<<256, 256, 0, stream>>>(pre, g_out, d_out, flagB);
}

// Round 5
// 476.613 us; speedup vs baseline: 3.2088x; 1.2490x over previous
//
#include <hip/hip_runtime.h>
#include <hip/hip_bf16.h>

typedef __hip_bfloat16 bf16;
typedef short bf16x8 __attribute__((ext_vector_type(8)));
typedef float f32x4 __attribute__((ext_vector_type(4)));

#define PTOT  65536   // b * h * w = 16 * 4096
#define NPOS  4096    // h * w
#define CIN   256
#define HID   512
#define HD    64

__device__ __forceinline__ float us2f(unsigned short u) {
    return __uint_as_float(((unsigned int)u) << 16);
}
__device__ __forceinline__ float ldf(const void* p, size_t i, bool bf) {
    return bf ? us2f(((const unsigned short*)p)[i]) : ((const float*)p)[i];
}
__device__ __forceinline__ unsigned short f2bs(float v) {
    __hip_bfloat16 h = __float2bfloat16(v);
    return *reinterpret_cast<unsigned short*>(&h);
}
// async global->LDS, 16 B per lane; lds dest must be wave-uniform base
__device__ __forceinline__ void gld16(const void* g, void* s) {
    __builtin_amdgcn_global_load_lds(
        (const __attribute__((address_space(1))) unsigned int*)g,
        (__attribute__((address_space(3))) unsigned int*)s, 16, 0, 0);
}

// ---------------------------------------------------------------- dtype detector
__global__ __launch_bounds__(256) void k_detect(const unsigned* __restrict__ x,
                                                int* __restrict__ flag) {
    int t = threadIdx.x;
    unsigned w = x[(size_t)t * 997];
    unsigned e7 = (w >> 8) & 0x7f;
    __shared__ int s[256];
    s[t] = (e7 >= 58 && e7 <= 66) ? 1 : 0;
    __syncthreads();
    for (int k = 128; k > 0; k >>= 1) { if (t < k) s[t] += s[t + k]; __syncthreads(); }
    if (t == 0) flag[0] = (s[0] >= 128) ? 1 : 0;
}

__global__ void k_relay(const int* __restrict__ src, int* __restrict__ dst) {
    dst[0] = src[0];
}

// ---------------------------------------------------------------- elementwise convert -> bf16
__global__ __launch_bounds__(256) void k_cvt(const void* __restrict__ src,
        unsigned short* __restrict__ dst, int n, const int* __restrict__ flag) {
    bool bf = flag[0] != 0;
    int i = blockIdx.x * 256 + threadIdx.x;
    if (i < n) dst[i] = f2bs(ldf(src, i, bf));
}

// ---------------------------------------------------------------- rmsnorm(x) -> xn bf16 [p][c] (c contiguous)
__global__ __launch_bounds__(256) void k_norm_xn(
        const void* __restrict__ x, const void* __restrict__ g,
        unsigned short* __restrict__ xn, const int* __restrict__ flag)
{
    bool bf = flag[0] != 0;
    __shared__ float xs[64][65];
    __shared__ float gS[256];
    __shared__ float sS[64];
    __shared__ float red[4][64];
    int t = threadIdx.x;
    int p0 = blockIdx.x * 64;
    int b = p0 >> 12;
    int posbase = p0 & 4095;
    gS[t] = ldf(g, t, bf);
    int pl = t & 63, cg = t >> 6;
    const size_t xbase = ((size_t)b * CIN) << 12;
    float ss = 0.f;
    for (int c = cg * 64; c < cg * 64 + 64; ++c) {
        float v = ldf(x, xbase + ((size_t)c << 12) + posbase + pl, bf);
        ss += v * v;
    }
    red[cg][pl] = ss;
    __syncthreads();
    if (t < 64) {
        float tot = red[0][t] + red[1][t] + red[2][t] + red[3][t];
        sS[t] = 16.0f / fmaxf(sqrtf(tot), 1e-12f);
    }
    for (int c0 = 0; c0 < 256; c0 += 64) {
        __syncthreads();
        #pragma unroll
        for (int r = 0; r < 16; ++r) {
            int c = c0 + r * 4 + cg;
            xs[r * 4 + cg][pl] = ldf(x, xbase + ((size_t)c << 12) + posbase + pl, bf);
        }
        __syncthreads();
        int pr = t >> 2, c4 = (t & 3) * 16;
        float sc = sS[pr];
        unsigned short tmp[16];
        #pragma unroll
        for (int j = 0; j < 16; ++j)
            tmp[j] = f2bs(xs[c4 + j][pr] * sc * gS[c0 + c4 + j]);
        unsigned short* dst = &xn[(size_t)(p0 + pr) * 256 + c0 + c4];
        *(uint4*)dst = ((uint4*)tmp)[0];
        *(uint4*)(dst + 8) = ((uint4*)tmp)[1];
    }
}

// ---------------------------------------------------------------- MFMA GEMM: C[m][p] = W[m][k] · Bm[p][k]^T
template<int KTOT, bool BIAS>
__global__ __launch_bounds__(256) void k_mfma(
        const bf16* __restrict__ W, const bf16* __restrict__ Bm,
        const void* __restrict__ bias, bf16* __restrict__ C,
        const int* __restrict__ flag)
{
    __shared__ __align__(16) unsigned short As[128 * 32];
    __shared__ __align__(16) unsigned short Bs[128 * 32];
    const int tid = threadIdx.x;
    const int wv = tid >> 6, lane = tid & 63;
    const int quad = lane >> 4, l16 = lane & 15;
    const int wm = wv >> 1, wn = wv & 1;
    const int m0 = blockIdx.y * 128, n0 = blockIdx.x * 128;
    f32x4 acc[4][4] = {};
    const bf16* gA = W + (size_t)(m0 + (tid >> 2)) * KTOT + (tid & 3) * 8;
    const bf16* gB = Bm + (size_t)(n0 + (tid >> 2)) * KTOT + (tid & 3) * 8;
    unsigned short* lA = As + wv * 512;
    unsigned short* lB = Bs + wv * 512;
    for (int k0 = 0; k0 < KTOT; k0 += 32) {
        gld16(gA + k0, lA);
        gld16(gA + (size_t)64 * KTOT + k0, lA + 2048);
        gld16(gB + k0, lB);
        gld16(gB + (size_t)64 * KTOT + k0, lB + 2048);
        __syncthreads();
        bf16x8 bfr[4];
        #pragma unroll
        for (int j = 0; j < 4; ++j)
            bfr[j] = *(const bf16x8*)&Bs[(wn * 64 + j * 16 + l16) * 32 + quad * 8];
        #pragma unroll
        for (int i = 0; i < 4; ++i) {
            bf16x8 af = *(const bf16x8*)&As[(wm * 64 + i * 16 + l16) * 32 + quad * 8];
            #pragma unroll
            for (int j = 0; j < 4; ++j)
                acc[i][j] = __builtin_amdgcn_mfma_f32_16x16x32_bf16(af, bfr[j], acc[i][j], 0, 0, 0);
        }
        __syncthreads();
    }
    bool bf = BIAS ? (flag[0] != 0) : false;
    #pragma unroll
    for (int i = 0; i < 4; ++i) {
        int row = m0 + wm * 64 + i * 16 + quad * 4;
        #pragma unroll
        for (int r = 0; r < 4; ++r) {
            float bv = BIAS ? ldf(bias, row + r, bf) : 0.0f;
            #pragma unroll
            for (int j = 0; j < 4; ++j) {
                int col = n0 + wn * 64 + j * 16 + l16;
                C[(size_t)(row + r) * PTOT + col] = __float2bfloat16(acc[i][j][r] + bv);
            }
        }
    }
}

// ---------------------------------------------------------------- k row stats (max, 1/sumexp) over n=4100
__global__ __launch_bounds__(256) void k_kstats(
        const bf16* __restrict__ kv, const void* __restrict__ memkv,
        float* __restrict__ rowmax, float* __restrict__ rowinv,
        const int* __restrict__ flag)
{
    bool bf = flag[0] != 0;
    int r = blockIdx.x;                 // b*512 + h*64 + d
    int b = r >> 9, hd = r & 511;
    const unsigned short* krow = (const unsigned short*)kv + (size_t)hd * PTOT + b * NPOS;
    int t = threadIdx.x;
    float vals[16];
    float m = -1e30f;
    #pragma unroll
    for (int i = 0; i < 16; ++i) {
        vals[i] = us2f(krow[t + (i << 8)]);
        m = fmaxf(m, vals[i]);
    }
    float mv = (t < 4) ? ldf(memkv, hd * 4 + t, bf) : -1e30f;
    m = fmaxf(m, mv);
    __shared__ float red[256];
    red[t] = m; __syncthreads();
    for (int s = 128; s > 0; s >>= 1) {
        if (t < s) red[t] = fmaxf(red[t], red[t + s]);
        __syncthreads();
    }
    float M = red[0]; __syncthreads();
    float sum = 0.f;
    #pragma unroll
    for (int i = 0; i < 16; ++i) sum += expf(vals[i] - M);
    if (t < 4) sum += expf(mv - M);
    red[t] = sum; __syncthreads();
    for (int s = 128; s > 0; s >>= 1) {
        if (t < s) red[t] += red[t + s];
        __syncthreads();
    }
    if (t == 0) { rowmax[r] = M; rowinv[r] = 1.0f / red[0]; }
}

// ---------------------------------------------------------------- context via MFMA:
// per (b,h): ct[d][e] = sum_n expf(K[d][n]-rm[d])*ri[d] * V[e][n]
// block = (bh, chunk of 1024 n); 4 waves, each a 32x32 quadrant (2x2 16x16 tiles)
__global__ __launch_bounds__(256) void k_context_mfma(
        const bf16* __restrict__ kv, const void* __restrict__ memkv,
        const float* __restrict__ rowmax, const float* __restrict__ rowinv,
        float* __restrict__ ctpart, const int* __restrict__ flag)
{
    bool bf = flag[0] != 0;
    int bh = blockIdx.x, chunk = blockIdx.y;
    int b = bh >> 3, h = bh & 7;
    __shared__ __align__(16) unsigned short As[4][64 * 32];   // K softmaxed, [panel kk][row d][32 n]
    __shared__ __align__(16) unsigned short Bs[4][64 * 32];   // V raw,      [panel kk][row e][32 n]
    __shared__ float rmS[64], riS[64];
    const int tid = threadIdx.x;
    if (tid < 64) {
        rmS[tid] = rowmax[(b << 9) + (h << 6) + tid];
        riS[tid] = rowinv[(b << 9) + (h << 6) + tid];
    }
    __syncthreads();
    const int wv = tid >> 6, lane = tid & 63;
    const int quad = lane >> 4, l16 = lane & 15;
    const int wm = wv >> 1, wn = wv & 1;
    const int krow = tid >> 2, kseg = tid & 3;
    const float rm = rmS[krow], ri = riS[krow];
    const unsigned short* kbase = (const unsigned short*)kv + (size_t)(h * HD) * PTOT + b * NPOS + chunk * 1024;
    const unsigned short* vbase = (const unsigned short*)kv + (size_t)(HID + h * HD) * PTOT + b * NPOS + chunk * 1024;
    f32x4 acc[2][2] = {};
    for (int s = 0; s < 8; ++s) {
        int nb = s * 128;
        // K staging with softmax transform: each thread 4 panels x 8 elements
        #pragma unroll
        for (int kk = 0; kk < 4; ++kk) {
            uint4 u = *(const uint4*)(kbase + (size_t)krow * PTOT + nb + kk * 32 + kseg * 8);
            unsigned short out[8];
            const unsigned short* us = (const unsigned short*)&u;
            #pragma unroll
            for (int e = 0; e < 8; ++e)
                out[e] = f2bs(expf(us2f(us[e]) - rm) * ri);
            *(uint4*)&As[kk][krow * 32 + kseg * 8] = *(uint4*)out;
        }
        // V staging raw via async global->LDS (lane l lands at base + 8l shorts = [l>>2 row][ (l&3)*8 ])
        #pragma unroll
        for (int kk = 0; kk < 4; ++kk)
            gld16(vbase + (size_t)(wv * 16 + (lane >> 2)) * PTOT + nb + kk * 32 + (lane & 3) * 8,
                  &Bs[kk][wv * 512]);
        __syncthreads();
        #pragma unroll
        for (int kk = 0; kk < 4; ++kk) {
            bf16x8 bfr[2];
            #pragma unroll
            for (int j = 0; j < 2; ++j)
                bfr[j] = *(const bf16x8*)&Bs[kk][(wn * 32 + j * 16 + l16) * 32 + quad * 8];
            #pragma unroll
            for (int i = 0; i < 2; ++i) {
                bf16x8 af = *(const bf16x8*)&As[kk][(wm * 32 + i * 16 + l16) * 32 + quad * 8];
                #pragma unroll
                for (int j = 0; j < 2; ++j)
                    acc[i][j] = __builtin_amdgcn_mfma_f32_16x16x32_bf16(af, bfr[j], acc[i][j], 0, 0, 0);
            }
        }
        __syncthreads();
    }
    if (chunk == 0) {   // memory K/V contribution (n = 0..3 of concat)
        float mv[2][4];
        #pragma unroll
        for (int j = 0; j < 2; ++j) {
            int e = wn * 32 + j * 16 + l16;
            #pragma unroll
            for (int mm = 0; mm < 4; ++mm)
                mv[j][mm] = ldf(memkv, 2048 + ((h << 6) + e) * 4 + mm, bf);
        }
        #pragma unroll
        for (int i = 0; i < 2; ++i) {
            #pragma unroll
            for (int r = 0; r < 4; ++r) {
                int d = wm * 32 + i * 16 + quad * 4 + r;
                #pragma unroll
                for (int mm = 0; mm < 4; ++mm) {
                    float kw = expf(ldf(memkv, ((h << 6) + d) * 4 + mm, bf) - rmS[d]) * riS[d];
                    #pragma unroll
                    for (int j = 0; j < 2; ++j)
                        acc[i][j][r] = fmaf(kw, mv[j][mm], acc[i][j][r]);
                }
            }
        }
    }
    float* outp = ctpart + (size_t)(chunk * 128 + bh) * 4096;
    #pragma unroll
    for (int i = 0; i < 2; ++i) {
        #pragma unroll
        for (int r = 0; r < 4; ++r) {
            int d = wm * 32 + i * 16 + quad * 4 + r;
            #pragma unroll
            for (int j = 0; j < 2; ++j) {
                int e = wn * 32 + j * 16 + l16;
                outp[d * 64 + e] = acc[i][j][r];
            }
        }
    }
}

// ---------------------------------------------------------------- q softmax + out; writes oat_pe [p][e] (e contiguous)
__global__ __launch_bounds__(256) void k_apply(
        const bf16* __restrict__ qbuf, const float* __restrict__ ctpart,
        unsigned short* __restrict__ oat_pe)
{
    int blk = blockIdx.x;
    int pt = blk & 15, h = (blk >> 4) & 7, b = blk >> 7;
    __shared__ float ctS[4096];   // [d][e]
    int tid = threadIdx.x;
    int bh = b * 8 + h;
    for (int l = 0; l < 16; ++l) {
        int idx = tid + (l << 8);
        float s = 0.f;
        #pragma unroll
        for (int c = 0; c < 4; ++c) s += ctpart[(size_t)(c * 128 + bh) * 4096 + idx];
        ctS[idx] = s;
    }
    __syncthreads();
    int n = pt * 256 + tid;
    const unsigned short* qbase = (const unsigned short*)qbuf + (size_t)(h * HD) * PTOT + b * NPOS + n;
    float qs[64];
    float m = -1e30f;
    #pragma unroll
    for (int d2 = 0; d2 < 64; ++d2) { qs[d2] = us2f(qbase[(size_t)d2 * PTOT]); m = fmaxf(m, qs[d2]); }
    float s = 0.f;
    #pragma unroll
    for (int d2 = 0; d2 < 64; ++d2) { qs[d2] = expf(qs[d2] - m); s += qs[d2]; }
    float inv = 0.125f / s;
    #pragma unroll
    for (int d2 = 0; d2 < 64; ++d2) qs[d2] *= inv;
    unsigned short* obase = oat_pe + (size_t)(b * NPOS + n) * HID + h * HD;
    #pragma unroll
    for (int ec = 0; ec < 4; ++ec) {
        float acc[16] = {};
        #pragma unroll
        for (int d2 = 0; d2 < 64; ++d2) {
            float qd = qs[d2];
            const float4* cr = (const float4*)&ctS[d2 * 64 + ec * 16];
            float4 c0 = cr[0], c1 = cr[1], c2 = cr[2], c3 = cr[3];
            acc[0]  = fmaf(qd, c0.x, acc[0]);  acc[1]  = fmaf(qd, c0.y, acc[1]);
            acc[2]  = fmaf(qd, c0.z, acc[2]);  acc[3]  = fmaf(qd, c0.w, acc[3]);
            acc[4]  = fmaf(qd, c1.x, acc[4]);  acc[5]  = fmaf(qd, c1.y, acc[5]);
            acc[6]  = fmaf(qd, c1.z, acc[6]);  acc[7]  = fmaf(qd, c1.w, acc[7]);
            acc[8]  = fmaf(qd, c2.x, acc[8]);  acc[9]  = fmaf(qd, c2.y, acc[9]);
            acc[10] = fmaf(qd, c2.z, acc[10]); acc[11] = fmaf(qd, c2.w, acc[11]);
            acc[12] = fmaf(qd, c3.x, acc[12]); acc[13] = fmaf(qd, c3.y, acc[13]);
            acc[14] = fmaf(qd, c3.z, acc[14]); acc[15] = fmaf(qd, c3.w, acc[15]);
        }
        unsigned short tmp[16];
        #pragma unroll
        for (int j = 0; j < 16; ++j) tmp[j] = f2bs(acc[j]);
        *(uint4*)(obase + ec * 16) = ((uint4*)tmp)[0];
        *(uint4*)(obase + ec * 16 + 8) = ((uint4*)tmp)[1];
    }
}

// ---------------------------------------------------------------- rmsnorm(pre bf16) -> d_out [b][c][pos]
template<bool BF>
__device__ __forceinline__ void rmsout_body(const unsigned short* pre, const void* g, void* out) {
    int p = blockIdx.x * 256 + threadIdx.x;
    int b = p >> 12, pos = p & 4095;
    float ss = 0.f;
    for (int c = 0; c < CIN; ++c) { float v = us2f(pre[(size_t)c * PTOT + p]); ss += v * v; }
    float scale = 16.0f / fmaxf(sqrtf(ss), 1e-12f);
    for (int c = 0; c < CIN; ++c) {
        float v = us2f(pre[(size_t)c * PTOT + p]) * scale * (BF ? us2f(((const unsigned short*)g)[c]) : ((const float*)g)[c]);
        size_t oi = ((size_t)(b * CIN + c) << 12) + pos;
        if (BF) ((unsigned short*)out)[oi] = f2bs(v);
        else    ((float*)out)[oi] = v;
    }
}
__global__ __launch_bounds__(256) void k_rmsnorm_out(
        const unsigned short* __restrict__ pre, const void* __restrict__ g,
        void* __restrict__ out, const int* __restrict__ flag)
{
    if (flag[0]) rmsout_body<true>(pre, g, out);
    else         rmsout_body<false>(pre, g, out);
}

extern "C" void kernel_launch(void* const* d_in, const int* in_sizes, int n_in,
                              void* d_out, int out_size, void* d_ws, size_t ws_size,
                              hipStream_t stream) {
    const void* x     = d_in[0];
    const void* g_in  = d_in[1];
    const void* w_qkv = d_in[2];
    const void* memkv = d_in[3];
    const void* w_out = d_in[4];
    const void* b_out = d_in[5];
    const void* g_out = d_in[6];

    // ---- workspace: peak 128 MiB ----
    char* ws = (char*)d_ws;
    bf16*           kv     = (bf16*)ws;                        // [1024][65536] bf16: K 0..511, V 512..1023
    bf16*           qbuf   = (bf16*)ws;                        // [512][65536] bf16, over dead K
    unsigned short* oat_pe = (unsigned short*)(ws + 67108864); // [65536][512] bf16, over dead V
    unsigned short* pre    = (unsigned short*)ws;              // [256][65536] bf16, over dead qbuf
    int*            flagB  = (int*)(ws + 50331648);            // dead zone at relay time

    // ---- scratch in d_out; all dead before final overwrite (layout validated R3/R4) ----
    char* ob = (char*)d_out;
    float*          ctpart = (float*)ob;                        // 8 MiB  [4][128][64][64]
    float*          rowmax = (float*)(ob + 8388608);            // 32 KiB
    float*          rowinv = (float*)(ob + 8421376);            // 32 KiB
    int*            flagA  = (int*)(ob + 8454144);              // 4 B
    unsigned short* wq_b   = (unsigned short*)(ob + 9437184);   // 768 KiB
    unsigned short* wout_b = (unsigned short*)(ob + 10485760);  // 256 KiB
    unsigned short* xn     = (unsigned short*)(ob + 12582912);  // [65536][256] bf16 = 32 MiB

    k_detect<<<1, 256, 0, stream>>>((const unsigned*)x, flagA);

    k_cvt<<<1536, 256, 0, stream>>>(w_qkv, wq_b, 1536 * 256, flagA);
    k_cvt<<<512, 256, 0, stream>>>(w_out, wout_b, 256 * 512, flagA);

    k_norm_xn<<<1024, 256, 0, stream>>>(x, g_in, xn, flagA);

    // K/V = w_qkv rows 512..1535: C[1024][PTOT]
    dim3 gkv(512, 8);
    k_mfma<CIN, false><<<gkv, 256, 0, stream>>>(
        (const bf16*)(wq_b + (size_t)512 * CIN), (const bf16*)xn, nullptr, kv, flagA);

    k_kstats<<<8192, 256, 0, stream>>>(kv, memkv, rowmax, rowinv, flagA);

    dim3 gctx(128, 4);
    k_context_mfma<<<gctx, 256, 0, stream>>>(kv, memkv, rowmax, rowinv, ctpart, flagA);

    // Q = w_qkv rows 0..511 (K region dead after context)
    dim3 gq(512, 4);
    k_mfma<CIN, false><<<gq, 256, 0, stream>>>(
        (const bf16*)wq_b, (const bf16*)xn, nullptr, qbuf, flagA);

    k_apply<<<2048, 256, 0, stream>>>(qbuf, ctpart, oat_pe);

    // pre[256][PTOT] = w_out[256][512] · oat_pe[p][512]^T + b_out
    dim3 go(512, 2);
    k_mfma<HID, true><<<go, 256, 0, stream>>>(
        (const bf16*)wout_b, (const bf16*)oat_pe, b_out, (bf16*)pre, flagA);

    k_relay<<<1, 1, 0, stream>>>(flagA, flagB);

    k_rmsnorm_out<<<256, 256, 0, stream>>>(pre, g_out, d_out, flagB);
}

// Round 6
// 415.228 us; speedup vs baseline: 3.6832x; 1.1478x over previous
//
#include <hip/hip_runtime.h>
#include <hip/hip_bf16.h>

typedef __hip_bfloat16 bf16;
typedef short bf16x8 __attribute__((ext_vector_type(8)));
typedef float f32x4 __attribute__((ext_vector_type(4)));

#define PTOT  65536   // b * h * w = 16 * 4096
#define NPOS  4096    // h * w
#define CIN   256
#define HID   512
#define HD    64

__device__ __forceinline__ float us2f(unsigned short u) {
    return __uint_as_float(((unsigned int)u) << 16);
}
__device__ __forceinline__ float ldf(const void* p, size_t i, bool bf) {
    return bf ? us2f(((const unsigned short*)p)[i]) : ((const float*)p)[i];
}
__device__ __forceinline__ unsigned short f2bs(float v) {
    __hip_bfloat16 h = __float2bfloat16(v);
    return *reinterpret_cast<unsigned short*>(&h);
}
// async global->LDS, 16 B per lane; lds dest must be wave-uniform base
__device__ __forceinline__ void gld16(const void* g, void* s) {
    __builtin_amdgcn_global_load_lds(
        (const __attribute__((address_space(1))) unsigned int*)g,
        (__attribute__((address_space(3))) unsigned int*)s, 16, 0, 0);
}

// ---------------------------------------------------------------- dtype detector
__global__ __launch_bounds__(256) void k_detect(const unsigned* __restrict__ x,
                                                int* __restrict__ flag) {
    int t = threadIdx.x;
    unsigned w = x[(size_t)t * 997];
    unsigned e7 = (w >> 8) & 0x7f;
    __shared__ int s[256];
    s[t] = (e7 >= 58 && e7 <= 66) ? 1 : 0;
    __syncthreads();
    for (int k = 128; k > 0; k >>= 1) { if (t < k) s[t] += s[t + k]; __syncthreads(); }
    if (t == 0) flag[0] = (s[0] >= 128) ? 1 : 0;
}

__global__ void k_relay(const int* __restrict__ src, int* __restrict__ dst) {
    dst[0] = src[0];
}

// ---------------------------------------------------------------- elementwise convert -> bf16
__global__ __launch_bounds__(256) void k_cvt(const void* __restrict__ src,
        unsigned short* __restrict__ dst, int n, const int* __restrict__ flag) {
    bool bf = flag[0] != 0;
    int i = blockIdx.x * 256 + threadIdx.x;
    if (i < n) dst[i] = f2bs(ldf(src, i, bf));
}

// ---------------------------------------------------------------- rmsnorm(x) -> xn bf16 [p][c] (c contiguous)
__global__ __launch_bounds__(256) void k_norm_xn(
        const void* __restrict__ x, const void* __restrict__ g,
        unsigned short* __restrict__ xn, const int* __restrict__ flag)
{
    bool bf = flag[0] != 0;
    __shared__ float xs[64][65];
    __shared__ float gS[256];
    __shared__ float sS[64];
    __shared__ float red[4][64];
    int t = threadIdx.x;
    int p0 = blockIdx.x * 64;
    int b = p0 >> 12;
    int posbase = p0 & 4095;
    gS[t] = ldf(g, t, bf);
    int pl = t & 63, cg = t >> 6;
    const size_t xbase = ((size_t)b * CIN) << 12;
    float ss = 0.f;
    for (int c = cg * 64; c < cg * 64 + 64; ++c) {
        float v = ldf(x, xbase + ((size_t)c << 12) + posbase + pl, bf);
        ss += v * v;
    }
    red[cg][pl] = ss;
    __syncthreads();
    if (t < 64) {
        float tot = red[0][t] + red[1][t] + red[2][t] + red[3][t];
        sS[t] = 16.0f / fmaxf(sqrtf(tot), 1e-12f);
    }
    for (int c0 = 0; c0 < 256; c0 += 64) {
        __syncthreads();
        #pragma unroll
        for (int r = 0; r < 16; ++r) {
            int c = c0 + r * 4 + cg;
            xs[r * 4 + cg][pl] = ldf(x, xbase + ((size_t)c << 12) + posbase + pl, bf);
        }
        __syncthreads();
        int pr = t >> 2, c4 = (t & 3) * 16;
        float sc = sS[pr];
        unsigned short tmp[16];
        #pragma unroll
        for (int j = 0; j < 16; ++j)
            tmp[j] = f2bs(xs[c4 + j][pr] * sc * gS[c0 + c4 + j]);
        unsigned short* dst = &xn[(size_t)(p0 + pr) * 256 + c0 + c4];
        *(uint4*)dst = ((uint4*)tmp)[0];
        *(uint4*)(dst + 8) = ((uint4*)tmp)[1];
    }
}

// ---------------------------------------------------------------- MFMA GEMM: C[m][n] = Am[m][k] · Bm[n][k]^T
// Am: [M][KTOT] bf16 rows k-contig; Bm: [N][KTOT] bf16 rows k-contig; C: [M][OSTRIDE] bf16
template<int KTOT, bool BIAS, int OSTRIDE>
__global__ __launch_bounds__(256) void k_mfma(
        const bf16* __restrict__ Am, const bf16* __restrict__ Bm,
        const void* __restrict__ bias, bf16* __restrict__ C,
        const int* __restrict__ flag)
{
    __shared__ __align__(16) unsigned short As[128 * 32];
    __shared__ __align__(16) unsigned short Bs[128 * 32];
    const int tid = threadIdx.x;
    const int wv = tid >> 6, lane = tid & 63;
    const int quad = lane >> 4, l16 = lane & 15;
    const int wm = wv >> 1, wn = wv & 1;
    const int m0 = blockIdx.y * 128, n0 = blockIdx.x * 128;
    f32x4 acc[4][4] = {};
    const bf16* gA = Am + (size_t)(m0 + (tid >> 2)) * KTOT + (tid & 3) * 8;
    const bf16* gB = Bm + (size_t)(n0 + (tid >> 2)) * KTOT + (tid & 3) * 8;
    unsigned short* lA = As + wv * 512;
    unsigned short* lB = Bs + wv * 512;
    for (int k0 = 0; k0 < KTOT; k0 += 32) {
        gld16(gA + k0, lA);
        gld16(gA + (size_t)64 * KTOT + k0, lA + 2048);
        gld16(gB + k0, lB);
        gld16(gB + (size_t)64 * KTOT + k0, lB + 2048);
        __syncthreads();
        bf16x8 bfr[4];
        #pragma unroll
        for (int j = 0; j < 4; ++j)
            bfr[j] = *(const bf16x8*)&Bs[(wn * 64 + j * 16 + l16) * 32 + quad * 8];
        #pragma unroll
        for (int i = 0; i < 4; ++i) {
            bf16x8 af = *(const bf16x8*)&As[(wm * 64 + i * 16 + l16) * 32 + quad * 8];
            #pragma unroll
            for (int j = 0; j < 4; ++j)
                acc[i][j] = __builtin_amdgcn_mfma_f32_16x16x32_bf16(af, bfr[j], acc[i][j], 0, 0, 0);
        }
        __syncthreads();
    }
    bool bf = BIAS ? (flag[0] != 0) : false;
    #pragma unroll
    for (int i = 0; i < 4; ++i) {
        int row = m0 + wm * 64 + i * 16 + quad * 4;
        #pragma unroll
        for (int r = 0; r < 4; ++r) {
            float bv = BIAS ? ldf(bias, row + r, bf) : 0.0f;
            #pragma unroll
            for (int j = 0; j < 4; ++j) {
                int col = n0 + wn * 64 + j * 16 + l16;
                C[(size_t)(row + r) * OSTRIDE + col] = __float2bfloat16(acc[i][j][r] + bv);
            }
        }
    }
}

// ---------------------------------------------------------------- k row stats (max, 1/sumexp) over n=4100
__global__ __launch_bounds__(256) void k_kstats(
        const bf16* __restrict__ kv, const void* __restrict__ memkv,
        float* __restrict__ rowmax, float* __restrict__ rowinv,
        const int* __restrict__ flag)
{
    bool bf = flag[0] != 0;
    int r = blockIdx.x;                 // b*512 + h*64 + d
    int b = r >> 9, hd = r & 511;
    const unsigned short* krow = (const unsigned short*)kv + (size_t)hd * PTOT + b * NPOS;
    int t = threadIdx.x;
    float vals[16];
    float m = -1e30f;
    #pragma unroll
    for (int i = 0; i < 16; ++i) {
        vals[i] = us2f(krow[t + (i << 8)]);
        m = fmaxf(m, vals[i]);
    }
    float mv = (t < 4) ? ldf(memkv, hd * 4 + t, bf) : -1e30f;
    m = fmaxf(m, mv);
    __shared__ float red[256];
    red[t] = m; __syncthreads();
    for (int s = 128; s > 0; s >>= 1) {
        if (t < s) red[t] = fmaxf(red[t], red[t + s]);
        __syncthreads();
    }
    float M = red[0]; __syncthreads();
    float sum = 0.f;
    #pragma unroll
    for (int i = 0; i < 16; ++i) sum += expf(vals[i] - M);
    if (t < 4) sum += expf(mv - M);
    red[t] = sum; __syncthreads();
    for (int s = 128; s > 0; s >>= 1) {
        if (t < s) red[t] += red[t + s];
        __syncthreads();
    }
    if (t == 0) { rowmax[r] = M; rowinv[r] = 1.0f / red[0]; }
}

// ---------------------------------------------------------------- context via MFMA (validated R5)
__global__ __launch_bounds__(256) void k_context_mfma(
        const bf16* __restrict__ kv, const void* __restrict__ memkv,
        const float* __restrict__ rowmax, const float* __restrict__ rowinv,
        float* __restrict__ ctpart, const int* __restrict__ flag)
{
    bool bf = flag[0] != 0;
    int bh = blockIdx.x, chunk = blockIdx.y;
    int b = bh >> 3, h = bh & 7;
    __shared__ __align__(16) unsigned short As[4][64 * 32];
    __shared__ __align__(16) unsigned short Bs[4][64 * 32];
    __shared__ float rmS[64], riS[64];
    const int tid = threadIdx.x;
    if (tid < 64) {
        rmS[tid] = rowmax[(b << 9) + (h << 6) + tid];
        riS[tid] = rowinv[(b << 9) + (h << 6) + tid];
    }
    __syncthreads();
    const int wv = tid >> 6, lane = tid & 63;
    const int quad = lane >> 4, l16 = lane & 15;
    const int wm = wv >> 1, wn = wv & 1;
    const int krow = tid >> 2, kseg = tid & 3;
    const float rm = rmS[krow], ri = riS[krow];
    const unsigned short* kbase = (const unsigned short*)kv + (size_t)(h * HD) * PTOT + b * NPOS + chunk * 1024;
    const unsigned short* vbase = (const unsigned short*)kv + (size_t)(HID + h * HD) * PTOT + b * NPOS + chunk * 1024;
    f32x4 acc[2][2] = {};
    for (int s = 0; s < 8; ++s) {
        int nb = s * 128;
        #pragma unroll
        for (int kk = 0; kk < 4; ++kk) {
            uint4 u = *(const uint4*)(kbase + (size_t)krow * PTOT + nb + kk * 32 + kseg * 8);
            unsigned short out[8];
            const unsigned short* us = (const unsigned short*)&u;
            #pragma unroll
            for (int e = 0; e < 8; ++e)
                out[e] = f2bs(expf(us2f(us[e]) - rm) * ri);
            *(uint4*)&As[kk][krow * 32 + kseg * 8] = *(uint4*)out;
        }
        #pragma unroll
        for (int kk = 0; kk < 4; ++kk)
            gld16(vbase + (size_t)(wv * 16 + (lane >> 2)) * PTOT + nb + kk * 32 + (lane & 3) * 8,
                  &Bs[kk][wv * 512]);
        __syncthreads();
        #pragma unroll
        for (int kk = 0; kk < 4; ++kk) {
            bf16x8 bfr[2];
            #pragma unroll
            for (int j = 0; j < 2; ++j)
                bfr[j] = *(const bf16x8*)&Bs[kk][(wn * 32 + j * 16 + l16) * 32 + quad * 8];
            #pragma unroll
            for (int i = 0; i < 2; ++i) {
                bf16x8 af = *(const bf16x8*)&As[kk][(wm * 32 + i * 16 + l16) * 32 + quad * 8];
                #pragma unroll
                for (int j = 0; j < 2; ++j)
                    acc[i][j] = __builtin_amdgcn_mfma_f32_16x16x32_bf16(af, bfr[j], acc[i][j], 0, 0, 0);
            }
        }
        __syncthreads();
    }
    if (chunk == 0) {
        float mv[2][4];
        #pragma unroll
        for (int j = 0; j < 2; ++j) {
            int e = wn * 32 + j * 16 + l16;
            #pragma unroll
            for (int mm = 0; mm < 4; ++mm)
                mv[j][mm] = ldf(memkv, 2048 + ((h << 6) + e) * 4 + mm, bf);
        }
        #pragma unroll
        for (int i = 0; i < 2; ++i) {
            #pragma unroll
            for (int r = 0; r < 4; ++r) {
                int d = wm * 32 + i * 16 + quad * 4 + r;
                #pragma unroll
                for (int mm = 0; mm < 4; ++mm) {
                    float kw = expf(ldf(memkv, ((h << 6) + d) * 4 + mm, bf) - rmS[d]) * riS[d];
                    #pragma unroll
                    for (int j = 0; j < 2; ++j)
                        acc[i][j][r] = fmaf(kw, mv[j][mm], acc[i][j][r]);
                }
            }
        }
    }
    float* outp = ctpart + (size_t)(chunk * 128 + bh) * 4096;
    #pragma unroll
    for (int i = 0; i < 2; ++i) {
        #pragma unroll
        for (int r = 0; r < 4; ++r) {
            int d = wm * 32 + i * 16 + quad * 4 + r;
            #pragma unroll
            for (int j = 0; j < 2; ++j) {
                int e = wn * 32 + j * 16 + l16;
                outp[d * 64 + e] = acc[i][j][r];
            }
        }
    }
}

// ---------------------------------------------------------------- sum ctpart chunks -> ct_bf [bh][e][d] bf16 (transposed)
__global__ __launch_bounds__(256) void k_ctsum(
        const float* __restrict__ ctpart, unsigned short* __restrict__ ct_bf)
{
    int bh = blockIdx.x, t = threadIdx.x;
    int i0 = t * 16;
    int e = i0 >> 6, d0 = i0 & 63;
    unsigned short tmp[16];
    #pragma unroll
    for (int j = 0; j < 16; ++j) {
        int d = d0 + j;
        float s = 0.f;
        #pragma unroll
        for (int c = 0; c < 4; ++c)
            s += ctpart[(size_t)(c * 128 + bh) * 4096 + d * 64 + e];
        tmp[j] = f2bs(s);
    }
    unsigned short* dst = ct_bf + (size_t)bh * 4096 + i0;
    *(uint4*)dst = ((uint4*)tmp)[0];
    *(uint4*)(dst + 8) = ((uint4*)tmp)[1];
}

// ---------------------------------------------------------------- q softmax + apply via MFMA
// block = (bh, chunk of 128 positions); out[p][e] = sum_d qsm[p][d] * ct[d][e]
__global__ __launch_bounds__(256) void k_apply_mfma(
        const unsigned short* __restrict__ qpe, const unsigned short* __restrict__ ct_bf,
        unsigned short* __restrict__ oat_pe)
{
    __shared__ __align__(16) unsigned short As[128 * 72];  // qsm [p][d], stride 72 (bank-safe)
    __shared__ __align__(16) unsigned short ctS[64 * 72];  // ct^T [e][d], stride 72
    __shared__ float pmax[2][128], psum[2][128];
    const int bh = blockIdx.x, chunk = blockIdx.y;
    const int b = bh >> 3, h = bh & 7;
    const int t = threadIdx.x;
    const size_t prow0 = (size_t)b * NPOS + chunk * 128;   // global row in qpe/oat_pe

    // stage ct (8 KB) into padded LDS
    {
        int i0 = t * 16;
        int e = i0 >> 6, d0 = i0 & 63;
        const unsigned short* src = ct_bf + (size_t)bh * 4096 + i0;
        uint4 u0 = *(const uint4*)src;
        uint4 u1 = *(const uint4*)(src + 8);
        *(uint4*)&ctS[e * 72 + d0] = u0;
        *(uint4*)&ctS[e * 72 + d0 + 8] = u1;
    }
    // q softmax: 2 threads per position (halves of d), bf16-pack into As
    const int posl = t & 127, half = t >> 7;
    {
        const unsigned short* qsrc = qpe + (prow0 + posl) * HID + h * HD + half * 32;
        uint4 u[4];
        u[0] = *(const uint4*)qsrc;
        u[1] = *(const uint4*)(qsrc + 8);
        u[2] = *(const uint4*)(qsrc + 16);
        u[3] = *(const uint4*)(qsrc + 24);
        const unsigned short* us = (const unsigned short*)u;
        float m = -1e30f;
        #pragma unroll
        for (int j = 0; j < 32; ++j) m = fmaxf(m, us2f(us[j]));
        pmax[half][posl] = m;
        __syncthreads();
        m = fmaxf(pmax[0][posl], pmax[1][posl]);
        float s = 0.f;
        #pragma unroll
        for (int j = 0; j < 32; ++j) s += expf(us2f(us[j]) - m);
        psum[half][posl] = s;
        __syncthreads();
        float inv = 0.125f / (psum[0][posl] + psum[1][posl]);
        unsigned short tmp[32];
        #pragma unroll
        for (int j = 0; j < 32; ++j) tmp[j] = f2bs(expf(us2f(us[j]) - m) * inv);
        unsigned short* dst = &As[posl * 72 + half * 32];
        #pragma unroll
        for (int q = 0; q < 4; ++q) *(uint4*)(dst + q * 8) = ((uint4*)tmp)[q];
    }
    __syncthreads();
    // MFMA: wave wv -> m-tiles {2wv, 2wv+1}; n-tiles 0..3; k = 64 (2 panels)
    const int wv = t >> 6, lane = t & 63;
    const int quad = lane >> 4, l16 = lane & 15;
    f32x4 acc[2][4] = {};
    #pragma unroll
    for (int kk = 0; kk < 2; ++kk) {
        bf16x8 bfr[4];
        #pragma unroll
        for (int j = 0; j < 4; ++j)
            bfr[j] = *(const bf16x8*)&ctS[(j * 16 + l16) * 72 + kk * 32 + quad * 8];
        #pragma unroll
        for (int i = 0; i < 2; ++i) {
            bf16x8 af = *(const bf16x8*)&As[(wv * 32 + i * 16 + l16) * 72 + kk * 32 + quad * 8];
            #pragma unroll
            for (int j = 0; j < 4; ++j)
                acc[i][j] = __builtin_amdgcn_mfma_f32_16x16x32_bf16(af, bfr[j], acc[i][j], 0, 0, 0);
        }
    }
    #pragma unroll
    for (int i = 0; i < 2; ++i) {
        #pragma unroll
        for (int r = 0; r < 4; ++r) {
            int prow = wv * 32 + i * 16 + quad * 4 + r;
            unsigned short* obase = oat_pe + (prow0 + prow) * HID + h * HD;
            #pragma unroll
            for (int j = 0; j < 4; ++j)
                obase[j * 16 + l16] = f2bs(acc[i][j][r]);
        }
    }
}

// ---------------------------------------------------------------- rmsnorm(pre bf16) -> d_out [b][c][pos]
template<bool BF>
__device__ __forceinline__ void rmsout_body(const unsigned short* pre, const void* g, void* out) {
    int p = blockIdx.x * 256 + threadIdx.x;
    int b = p >> 12, pos = p & 4095;
    float ss = 0.f;
    for (int c = 0; c < CIN; ++c) { float v = us2f(pre[(size_t)c * PTOT + p]); ss += v * v; }
    float scale = 16.0f / fmaxf(sqrtf(ss), 1e-12f);
    for (int c = 0; c < CIN; ++c) {
        float v = us2f(pre[(size_t)c * PTOT + p]) * scale * (BF ? us2f(((const unsigned short*)g)[c]) : ((const float*)g)[c]);
        size_t oi = ((size_t)(b * CIN + c) << 12) + pos;
        if (BF) ((unsigned short*)out)[oi] = f2bs(v);
        else    ((float*)out)[oi] = v;
    }
}
__global__ __launch_bounds__(256) void k_rmsnorm_out(
        const unsigned short* __restrict__ pre, const void* __restrict__ g,
        void* __restrict__ out, const int* __restrict__ flag)
{
    if (flag[0]) rmsout_body<true>(pre, g, out);
    else         rmsout_body<false>(pre, g, out);
}

extern "C" void kernel_launch(void* const* d_in, const int* in_sizes, int n_in,
                              void* d_out, int out_size, void* d_ws, size_t ws_size,
                              hipStream_t stream) {
    const void* x     = d_in[0];
    const void* g_in  = d_in[1];
    const void* w_qkv = d_in[2];
    const void* memkv = d_in[3];
    const void* w_out = d_in[4];
    const void* b_out = d_in[5];
    const void* g_out = d_in[6];

    // ---- workspace: peak 128 MiB ----
    char* ws = (char*)d_ws;
    bf16*           kv     = (bf16*)ws;                        // [1024][65536] bf16: K 0..511, V 512..1023
    unsigned short* qpe    = (unsigned short*)ws;              // [65536][512] bf16, over dead K
    unsigned short* oat_pe = (unsigned short*)(ws + 67108864); // [65536][512] bf16, over dead V
    unsigned short* pre    = (unsigned short*)ws;              // [256][65536] bf16, over dead qpe
    int*            flagB  = (int*)(ws + 50331648);            // dead zone at relay time

    // ---- scratch in d_out (fp32 out = 67 MB; layout validated R3-R5) ----
    char* ob = (char*)d_out;
    float*          ctpart = (float*)ob;                        // 8 MiB  [4][128][64][64]
    float*          rowmax = (float*)(ob + 8388608);            // 32 KiB
    float*          rowinv = (float*)(ob + 8421376);            // 32 KiB
    int*            flagA  = (int*)(ob + 8454144);              // 4 B
    unsigned short* wq_b   = (unsigned short*)(ob + 9437184);   // 768 KiB
    unsigned short* wout_b = (unsigned short*)(ob + 10485760);  // 256 KiB
    unsigned short* ct_bf  = (unsigned short*)(ob + 11010048);  // 1 MiB [128][64 e][64 d]
    unsigned short* xn     = (unsigned short*)(ob + 12582912);  // [65536][256] bf16 = 32 MiB

    k_detect<<<1, 256, 0, stream>>>((const unsigned*)x, flagA);

    k_cvt<<<1536, 256, 0, stream>>>(w_qkv, wq_b, 1536 * 256, flagA);
    k_cvt<<<512, 256, 0, stream>>>(w_out, wout_b, 256 * 512, flagA);

    k_norm_xn<<<1024, 256, 0, stream>>>(x, g_in, xn, flagA);

    // K/V = w_qkv rows 512..1535: C[1024][PTOT]
    dim3 gkv(512, 8);
    k_mfma<CIN, false, PTOT><<<gkv, 256, 0, stream>>>(
        (const bf16*)(wq_b + (size_t)512 * CIN), (const bf16*)xn, nullptr, kv, flagA);

    k_kstats<<<8192, 256, 0, stream>>>(kv, memkv, rowmax, rowinv, flagA);

    dim3 gctx(128, 4);
    k_context_mfma<<<gctx, 256, 0, stream>>>(kv, memkv, rowmax, rowinv, ctpart, flagA);

    k_ctsum<<<128, 256, 0, stream>>>(ctpart, ct_bf);

    // Q in [p][512] layout: A = xn rows p, B = w_qkv rows 0..511 -> C[p][o]
    dim3 gq(4, 512);
    k_mfma<CIN, false, HID><<<gq, 256, 0, stream>>>(
        (const bf16*)xn, (const bf16*)wq_b, nullptr, (bf16*)qpe, flagA);

    dim3 gap(128, 32);
    k_apply_mfma<<<gap, 256, 0, stream>>>(qpe, ct_bf, oat_pe);

    // pre[256][PTOT] = w_out[256][512] · oat_pe[p][512]^T + b_out
    dim3 go(512, 2);
    k_mfma<HID, true, PTOT><<<go, 256, 0, stream>>>(
        (const bf16*)wout_b, (const bf16*)oat_pe, b_out, (bf16*)pre, flagA);

    k_relay<<<1, 1, 0, stream>>>(flagA, flagB);

    k_rmsnorm_out<<<256, 256, 0, stream>>>(pre, g_out, d_out, flagB);
}